// Round 5
// baseline (277.564 us; speedup 1.0000x reference)
//
#include <hip/hip_runtime.h>
#include <math.h>

#define B_ROWS   1024
#define DIM      192
#define NCLS     100000
#define S_SCALE  30.0f
#define COS_M    0.98006657784124163f
#define SIN_M    0.19866933079506122f
#define TH_C     (-0.98006657784124163f)
#define MM_C     0.039733866159012243f
#define L2E30    43.2808512266689f      // 30 * log2(e)

#define NTILE_B  784      // 128-class tiles (784*128 = 100352)
#define NCHUNKR  16       // 64-row chunks of A
#define ASEG_CH  1536     // segs per A chunk: 24 k8-groups * 64 rows
#define BSEG_T   3072     // segs per B tile: 24 k8-groups * 128 cols

typedef float floatx4 __attribute__((ext_vector_type(4)));
typedef __bf16 bf16x8 __attribute__((ext_vector_type(8)));

__device__ __forceinline__ unsigned int f2bf(float x) {
    unsigned int u = __float_as_uint(x);
    u = (u + 0x7fffu + ((u >> 16) & 1u)) >> 16;   // RNE
    return u;
}
__device__ __forceinline__ unsigned int pack2(float lo, float hi) {
    return f2bf(lo) | (f2bf(hi) << 16);
}
__device__ __forceinline__ void gll16(const void* g, void* l) {
    __builtin_amdgcn_global_load_lds(
        (const __attribute__((address_space(1))) unsigned int*)g,
        (__attribute__((address_space(3))) unsigned int*)l, 16, 0, 0);
}
// 16-lane rotate (DPP row_ror:N) — reduction over the C-layout col lanes
// without touching the LDS pipe. After 4 stages all 16 lanes hold the total.
template <int N>
__device__ __forceinline__ float ror16(float x) {
    return __int_as_float(__builtin_amdgcn_mov_dpp(
        __float_as_int(x), 0x120 | N, 0xF, 0xF, false));
}

// ---------------------------------------------------------------------------
// Fused prep: L2-normalize + bf16 pack + MFMA-order swizzle, single pass.
// Blocks 0..783: B tiles (seg = k8*128 + col). Blocks 784..791: A (two 64-row
// chunks per block, seg = chunk*1536 + k8*64 + r64) + fp32 xnf for finalize.
// ---------------------------------------------------------------------------
__global__ __launch_bounds__(256)
void prep_kernel(const float* __restrict__ x, const float* __restrict__ w,
                 float* __restrict__ xnf, float* __restrict__ winv,
                 unsigned short* __restrict__ bsw, unsigned short* __restrict__ asw)
{
    const int b = blockIdx.x;
    const int t = threadIdx.x;
    const int r = t >> 1, half = t & 1;

    if (b < NTILE_B) {
        const int row = b * 128 + r;
        const bool live = (row < NCLS);
        float4 buf[24];
        float s = 0.f;
        if (live) {
            const float4* sp = (const float4*)(w + (size_t)row * DIM) + half * 24;
            #pragma unroll
            for (int q = 0; q < 24; ++q) {
                float4 v = sp[q];
                buf[q] = v;
                s += v.x * v.x + v.y * v.y + v.z * v.z + v.w * v.w;
            }
        }
        s += __shfl_xor(s, 1);
        const float inv = live ? (1.0f / fmaxf(sqrtf(s), 1e-12f)) : 0.0f;
        if (live && half == 0) winv[row] = inv;
        unsigned short* dst = bsw + (size_t)b * BSEG_T * 8;
        #pragma unroll
        for (int j = 0; j < 12; ++j) {
            const int k8 = half * 12 + j;
            uint4 o = make_uint4(0u, 0u, 0u, 0u);
            if (live) {
                float4 a0 = buf[2 * j], a1 = buf[2 * j + 1];
                o.x = pack2(a0.x * inv, a0.y * inv);
                o.y = pack2(a0.z * inv, a0.w * inv);
                o.z = pack2(a1.x * inv, a1.y * inv);
                o.w = pack2(a1.z * inv, a1.w * inv);
            }
            *(uint4*)(dst + (size_t)(k8 * 128 + r) * 8) = o;
        }
    } else {
        const int ab = b - NTILE_B;           // 0..7
        const int row = ab * 128 + r;
        const int c = ab * 2 + (r >> 6);      // A chunk index
        const int r64 = r & 63;
        float4 buf[24];
        float s = 0.f;
        const float4* sp = (const float4*)(x + (size_t)row * DIM) + half * 24;
        #pragma unroll
        for (int q = 0; q < 24; ++q) {
            float4 v = sp[q];
            buf[q] = v;
            s += v.x * v.x + v.y * v.y + v.z * v.z + v.w * v.w;
        }
        s += __shfl_xor(s, 1);
        const float inv = 1.0f / fmaxf(sqrtf(s), 1e-12f);
        float4* xd = (float4*)(xnf + (size_t)row * DIM) + half * 24;
        #pragma unroll
        for (int q = 0; q < 24; ++q)
            xd[q] = make_float4(buf[q].x * inv, buf[q].y * inv,
                                buf[q].z * inv, buf[q].w * inv);
        #pragma unroll
        for (int j = 0; j < 12; ++j) {
            const int k8 = half * 12 + j;
            uint4 o;
            float4 a0 = buf[2 * j], a1 = buf[2 * j + 1];
            o.x = pack2(a0.x * inv, a0.y * inv);
            o.y = pack2(a0.z * inv, a0.w * inv);
            o.z = pack2(a1.x * inv, a1.y * inv);
            o.w = pack2(a1.z * inv, a1.w * inv);
            *(uint4*)(asw + ((size_t)c * ASEG_CH + k8 * 64 + r64) * 8) = o;
        }
    }
}

// ---------------------------------------------------------------------------
// GEMM + fused fixed-base softmax stats, B-read-once blocking.
// One block per 128-class tile; all 1024 rows streamed in 16 chunks of 64.
// B fragments live in registers (96 VGPR/wave); A double-buffered in LDS.
// 4 waves = 2 row-groups (32 rows, mi=2) x 2 col-groups (64 cols, ni=4).
// ---------------------------------------------------------------------------
__global__ __launch_bounds__(256, 2)
void gemm_stats_kernel(const unsigned short* __restrict__ asw,
                       const unsigned short* __restrict__ bsw,
                       float2* __restrict__ pslot)
{
    __shared__ __align__(16) char lds[49152 + 2048];  // 2x24KB A dbuf + stats
    const int tid  = threadIdx.x;
    const int wave = tid >> 6;
    const int lane = tid & 63;
    const int quad = lane >> 4;
    const int mrow = lane & 15;
    const int rg   = wave >> 1;     // row group (32 rows)
    const int cgr  = wave & 1;      // col group (64 cols)
    float2* statsL = (float2*)(lds + 49152);   // [pp][64 rows][2 cgr]

    // ---- stage B tile (48KB) into the A-dbuf space, pull frags to regs ----
    const char* btile = (const char*)bsw + (size_t)blockIdx.x * (BSEG_T * 16);
    #pragma unroll
    for (int j = 0; j < 12; ++j)
        gll16(btile + (j * 256 + tid) * 16, lds + (j * 256 + tid) * 16);
    __syncthreads();
    bf16x8 bfr[6][4];
    #pragma unroll
    for (int ks = 0; ks < 6; ++ks)
        #pragma unroll
        for (int ni = 0; ni < 4; ++ni)
            bfr[ks][ni] = *(const bf16x8*)(lds +
                (((ks * 4 + quad) * 128) + cgr * 64 + ni * 16 + mrow) * 16);
    __syncthreads();

    // ---- preload A chunk 0 into buf0 ----
    const char* aswb = (const char*)asw;
    #pragma unroll
    for (int j = 0; j < 6; ++j)
        gll16(aswb + (j * 256 + tid) * 16, lds + (j * 256 + tid) * 16);

    for (int c = 0; c < NCHUNKR; ++c) {
        const int p = c & 1;
        __syncthreads();   // chunk c resident; prev compute done; stats c-1 visible

        // prefetch chunk c+1 (flies under the MFMA phase)
        if (c + 1 < NCHUNKR) {
            const char* src = aswb + (size_t)(c + 1) * ASEG_CH * 16;
            char* dstb = lds + (1 - p) * 24576;
            #pragma unroll
            for (int j = 0; j < 6; ++j)
                gll16(src + (j * 256 + tid) * 16, dstb + (j * 256 + tid) * 16);
        }
        // wave0: merge + write out chunk c-1 stats (ping-pong buffer 1-p)
        if (c > 0 && wave == 0) {
            float4 q4 = *(const float4*)&statsL[((1 - p) * 64 + lane) * 2];
            pslot[(size_t)blockIdx.x * B_ROWS + (c - 1) * 64 + lane] =
                make_float2(fmaxf(q4.x, q4.z), q4.y + q4.w);
        }

        // ---- compute chunk c ----
        const char* ab = lds + p * 24576;
        floatx4 acc[2][4];
        #pragma unroll
        for (int mi = 0; mi < 2; ++mi)
            #pragma unroll
            for (int ni = 0; ni < 4; ++ni) {
                floatx4 z = {0.f, 0.f, 0.f, 0.f};
                acc[mi][ni] = z;
            }
        #pragma unroll
        for (int ks = 0; ks < 6; ++ks) {
            bf16x8 a0 = *(const bf16x8*)(ab +
                (((ks * 4 + quad) * 64) + rg * 32 + mrow) * 16);
            bf16x8 a1 = *(const bf16x8*)(ab +
                (((ks * 4 + quad) * 64) + rg * 32 + 16 + mrow) * 16);
            #pragma unroll
            for (int ni = 0; ni < 4; ++ni)
                acc[0][ni] = __builtin_amdgcn_mfma_f32_16x16x32_bf16(
                    a0, bfr[ks][ni], acc[0][ni], 0, 0, 0);
            #pragma unroll
            for (int ni = 0; ni < 4; ++ni)
                acc[1][ni] = __builtin_amdgcn_mfma_f32_16x16x32_bf16(
                    a1, bfr[ks][ni], acc[1][ni], 0, 0, 0);
        }

        // ---- epilogue: fixed-base-30 stats, DPP rotate-reduce over 16 lanes ----
        #pragma unroll
        for (int mi = 0; mi < 2; ++mi)
            #pragma unroll
            for (int r = 0; r < 4; ++r) {
                float v0 = acc[mi][0][r], v1 = acc[mi][1][r];
                float v2 = acc[mi][2][r], v3 = acc[mi][3][r];
                float m = fmaxf(fmaxf(v0, v1), fmaxf(v2, v3));
                float s = exp2f(fmaf(v0, L2E30, -L2E30))
                        + exp2f(fmaf(v1, L2E30, -L2E30))
                        + exp2f(fmaf(v2, L2E30, -L2E30))
                        + exp2f(fmaf(v3, L2E30, -L2E30));
                s += ror16<1>(s); s += ror16<2>(s);
                s += ror16<4>(s); s += ror16<8>(s);
                m = fmaxf(m, ror16<1>(m)); m = fmaxf(m, ror16<2>(m));
                m = fmaxf(m, ror16<4>(m)); m = fmaxf(m, ror16<8>(m));
                if (mrow == mi * 4 + r)
                    statsL[(p * 64 + rg * 32 + mi * 16 + quad * 4 + r) * 2 + cgr] =
                        make_float2(m, s);
            }
    }
    __syncthreads();
    if (wave == 0) {   // last chunk (parity 1)
        float4 q4 = *(const float4*)&statsL[(64 + lane) * 2];
        pslot[(size_t)blockIdx.x * B_ROWS + (NCHUNKR - 1) * 64 + lane] =
            make_float2(fmaxf(q4.x, q4.z), q4.y + q4.w);
    }
}

// ---------------------------------------------------------------------------
// Finalize: merge 784 partials/row (fixed base -> plain add/max), ArcFace
// margin correction, loss+prec1; last block writes d_out (counter trick).
// grid(16) x 256: 64 rows/block, 4 slot-groups, coalesced slot-major reads.
// ---------------------------------------------------------------------------
__global__ __launch_bounds__(256)
void finalize_kernel(const float2* __restrict__ pslot,
                     const float* __restrict__ xnf, const float* __restrict__ w,
                     const float* __restrict__ winv, const int* __restrict__ label,
                     float* __restrict__ accum, float* __restrict__ out)
{
    __shared__ float2 red[4][64];
    const int t = threadIdx.x, rr = t & 63, g = t >> 6;
    {
        const int row = blockIdx.x * 64 + rr;
        float M = -1e30f, L = 0.f;
        for (int s = g; s < NTILE_B; s += 4) {
            float2 p2 = pslot[(size_t)s * B_ROWS + row];
            M = fmaxf(M, p2.x);
            L += p2.y;
        }
        red[g][rr] = make_float2(M, L);
    }
    __syncthreads();
    if (t < 64) {
        const int row = blockIdx.x * 64 + t;
        float2 p0 = red[0][t], p1 = red[1][t], p2 = red[2][t], p3 = red[3][t];
        float Mc = fmaxf(fmaxf(p0.x, p1.x), fmaxf(p2.x, p3.x));  // max cosine
        float L  = p0.y + p1.y + p2.y + p3.y;

        const int lab = label[row];
        const float4* xr = (const float4*)(xnf + (size_t)row * DIM);
        const float4* wr = (const float4*)(w + (size_t)lab * DIM);
        float dot = 0.f;
        #pragma unroll
        for (int q = 0; q < 48; ++q) {
            float4 a = xr[q], b = wr[q];
            dot += a.x * b.x + a.y * b.y + a.z * b.z + a.w * b.w;
        }
        float cosl    = dot * winv[lab];
        float t_plain = S_SCALE * cosl;
        float sine    = sqrtf(fmaxf(0.f, fminf(1.f, 1.f - cosl * cosl)));
        float phi     = cosl * COS_M - sine * SIN_M;
        float modv    = ((cosl - TH_C) > 0.f) ? phi : (cosl - MM_C);
        float t_mod   = S_SCALE * modv;

        float Ladj = L - __expf(t_plain - 30.0f) + __expf(t_mod - 30.0f);
        Ladj = fmaxf(Ladj, 1e-37f);
        float loss = (30.0f + logf(Ladj)) - t_mod;
        float corr = (t_mod > S_SCALE * Mc) ? 1.f : 0.f;

        #pragma unroll
        for (int off = 32; off > 0; off >>= 1) {
            loss += __shfl_xor(loss, off);
            corr += __shfl_xor(corr, off);
        }
        if (t == 0) {
            atomicAdd(&accum[0], loss);
            atomicAdd(&accum[1], corr);
            __threadfence();
            int old = atomicAdd((int*)accum + 2, 1);
            if (old == (int)gridDim.x - 1) {
                float a0 = atomicAdd(&accum[0], 0.0f);
                float a1 = atomicAdd(&accum[1], 0.0f);
                out[0] = a0 * (1.0f / (float)B_ROWS);
                out[1] = a1 * (100.0f / (float)B_ROWS);
            }
        }
    }
}

// ---------------------------------------------------------------------------
extern "C" void kernel_launch(void* const* d_in, const int* in_sizes, int n_in,
                              void* d_out, int out_size, void* d_ws, size_t ws_size,
                              hipStream_t stream)
{
    const float* x     = (const float*)d_in[0];
    const float* w     = (const float*)d_in[1];
    const int*   label = (const int*)d_in[2];
    float* out = (float*)d_out;

    char* ws = (char*)d_ws;
    size_t off = 0;
    float* accum = (float*)(ws + off);                 off += 256;
    float* xnf   = (float*)(ws + off);                 off += (size_t)B_ROWS * DIM * 4;     // 786432
    float* winv  = (float*)(ws + off);                 off += 400128;
    unsigned short* asw = (unsigned short*)(ws + off); off += (size_t)NCHUNKR * ASEG_CH * 16; // 393216
    unsigned short* bsw = (unsigned short*)(ws + off); off += (size_t)NTILE_B * BSEG_T * 16;  // 38535168
    float2* pslot = (float2*)(ws + off);               off += (size_t)NTILE_B * B_ROWS * 8;   // 6422528

    hipMemsetAsync(accum, 0, 16, stream);

    prep_kernel<<<dim3(NTILE_B + 8), dim3(256), 0, stream>>>(
        x, w, xnf, winv, bsw, asw);
    gemm_stats_kernel<<<dim3(NTILE_B), dim3(256), 0, stream>>>(asw, bsw, pslot);
    finalize_kernel<<<dim3(B_ROWS / 64), dim3(256), 0, stream>>>(
        pslot, xnf, w, winv, label, accum, out);
}

// Round 6
// 261.635 us; speedup vs baseline: 1.0609x; 1.0609x over previous
//
#include <hip/hip_runtime.h>
#include <math.h>

#define B_ROWS   1024
#define DIM      192
#define NCLS     100000
#define S_SCALE  30.0f
#define COS_M    0.98006657784124163f
#define SIN_M    0.19866933079506122f
#define TH_C     (-0.98006657784124163f)
#define MM_C     0.039733866159012243f
#define L2E30    43.2808512266689f      // 30 * log2(e)

#define NTILE_B  784      // 128-class tiles (784*128 = 100352)
#define NCHUNKR  16       // 64-row chunks of A
#define ASEG_CH  1536     // segs per A chunk: 24 k8-groups * 64 rows

typedef float floatx4 __attribute__((ext_vector_type(4)));
typedef __bf16 bf16x8 __attribute__((ext_vector_type(8)));

__device__ __forceinline__ unsigned int f2bf(float x) {
    unsigned int u = __float_as_uint(x);
    u = (u + 0x7fffu + ((u >> 16) & 1u)) >> 16;   // RNE
    return u;
}
__device__ __forceinline__ unsigned int pack2(float lo, float hi) {
    return f2bf(lo) | (f2bf(hi) << 16);
}
__device__ __forceinline__ void gll16(const void* g, void* l) {
    __builtin_amdgcn_global_load_lds(
        (const __attribute__((address_space(1))) unsigned int*)g,
        (__attribute__((address_space(3))) unsigned int*)l, 16, 0, 0);
}
// 16-lane rotate (DPP row_ror:N) — reduce over the C-layout col lanes
template <int N>
__device__ __forceinline__ float ror16(float x) {
    return __int_as_float(__builtin_amdgcn_mov_dpp(
        __float_as_int(x), 0x120 | N, 0xF, 0xF, false));
}

// ---------------------------------------------------------------------------
// Prep (x only): L2-normalize + bf16 pack + MFMA-order swizzle; writes fp32
// xnf (for finalize) and swizzled bf16 asw. 8 blocks x 256 threads.
// Thread pair (2r, 2r+1) owns row r; each thread holds half a row.
// ---------------------------------------------------------------------------
__global__ __launch_bounds__(256)
void prep_kernel(const float* __restrict__ x,
                 float* __restrict__ xnf, unsigned short* __restrict__ asw)
{
    const int ab = blockIdx.x;            // 0..7
    const int t = threadIdx.x;
    const int r = t >> 1, half = t & 1;
    const int row = ab * 128 + r;
    const int c = ab * 2 + (r >> 6);      // A chunk index (64-row chunks)
    const int r64 = r & 63;

    float4 buf[24];
    float s = 0.f;
    const float4* sp = (const float4*)(x + (size_t)row * DIM) + half * 24;
    #pragma unroll
    for (int q = 0; q < 24; ++q) {
        float4 v = sp[q];
        buf[q] = v;
        s += v.x * v.x + v.y * v.y + v.z * v.z + v.w * v.w;
    }
    s += __shfl_xor(s, 1);
    const float inv = 1.0f / fmaxf(sqrtf(s), 1e-12f);
    float4* xd = (float4*)(xnf + (size_t)row * DIM) + half * 24;
    #pragma unroll
    for (int q = 0; q < 24; ++q)
        xd[q] = make_float4(buf[q].x * inv, buf[q].y * inv,
                            buf[q].z * inv, buf[q].w * inv);
    #pragma unroll
    for (int j = 0; j < 12; ++j) {
        const int k8 = half * 12 + j;
        uint4 o;
        float4 a0 = buf[2 * j], a1 = buf[2 * j + 1];
        o.x = pack2(a0.x * inv, a0.y * inv);
        o.y = pack2(a0.z * inv, a0.w * inv);
        o.z = pack2(a1.x * inv, a1.y * inv);
        o.w = pack2(a1.z * inv, a1.w * inv);
        *(uint4*)(asw + ((size_t)c * ASEG_CH + k8 * 64 + r64) * 8) = o;
    }
}

// ---------------------------------------------------------------------------
// GEMM + fused fixed-base softmax stats, B-read-once + in-kernel B prep.
// One block per 128-class tile. Phase 1: each thread reads its half of a raw
// fp32 w row (read ONCE grid-wide), computes the pair norm, packs bf16 segs
// straight into LDS B-layout. Phase 2: pull B frags to registers (96 VGPR).
// Phase 3: stream all 1024 A rows in 16 chunks of 64 through a 2x24KB LDS
// double buffer (L2-resident asw), MFMA, per-chunk DPP-reduced stats.
// ---------------------------------------------------------------------------
__global__ __launch_bounds__(256, 2)
void gemm_stats_kernel(const float* __restrict__ w,
                       const unsigned short* __restrict__ asw,
                       float2* __restrict__ pslot)
{
    __shared__ __align__(16) char lds[49152 + 2048];  // 48KB B/A space + stats
    const int tid  = threadIdx.x;
    const int wave = tid >> 6;
    const int lane = tid & 63;
    const int quad = lane >> 4;
    const int mrow = lane & 15;
    const int rg   = wave >> 1;     // row group (32 rows)
    const int cgr  = wave & 1;      // col group (64 cols)
    float2* statsL = (float2*)(lds + 49152);   // [pp][64 rows][2 cgr]

    // ---- phase 1: normalize + pack this block's 128 w rows into LDS ----
    {
        const int r = tid >> 1, half = tid & 1;
        const int col = blockIdx.x * 128 + r;
        const bool live = (col < NCLS);
        float4 buf[24];
        float s = 0.f;
        if (live) {
            const float4* sp = (const float4*)(w + (size_t)col * DIM) + half * 24;
            #pragma unroll
            for (int q = 0; q < 24; ++q) {
                float4 v = sp[q];
                buf[q] = v;
                s += v.x * v.x + v.y * v.y + v.z * v.z + v.w * v.w;
            }
        }
        s += __shfl_xor(s, 1);
        const float inv = live ? (1.0f / fmaxf(sqrtf(s), 1e-12f)) : 0.0f;
        #pragma unroll
        for (int j = 0; j < 12; ++j) {
            const int k8 = half * 12 + j;
            uint4 o = make_uint4(0u, 0u, 0u, 0u);
            if (live) {
                float4 a0 = buf[2 * j], a1 = buf[2 * j + 1];
                o.x = pack2(a0.x * inv, a0.y * inv);
                o.y = pack2(a0.z * inv, a0.w * inv);
                o.z = pack2(a1.x * inv, a1.y * inv);
                o.w = pack2(a1.z * inv, a1.w * inv);
            }
            *(uint4*)(lds + (size_t)(k8 * 128 + r) * 16) = o;
        }
    }
    __syncthreads();

    // ---- phase 2: pull B fragments to registers ----
    bf16x8 bfr[6][4];
    #pragma unroll
    for (int ks = 0; ks < 6; ++ks)
        #pragma unroll
        for (int ni = 0; ni < 4; ++ni)
            bfr[ks][ni] = *(const bf16x8*)(lds +
                (((ks * 4 + quad) * 128) + cgr * 64 + ni * 16 + mrow) * 16);
    __syncthreads();

    // ---- phase 3: stream A; preload chunk 0 into buf0 ----
    const char* aswb = (const char*)asw;
    #pragma unroll
    for (int j = 0; j < 6; ++j)
        gll16(aswb + (j * 256 + tid) * 16, lds + (j * 256 + tid) * 16);

    for (int c = 0; c < NCHUNKR; ++c) {
        const int p = c & 1;
        __syncthreads();   // chunk c resident; prev compute done; stats c-1 visible

        if (c + 1 < NCHUNKR) {
            const char* src = aswb + (size_t)(c + 1) * ASEG_CH * 16;
            char* dstb = lds + (1 - p) * 24576;
            #pragma unroll
            for (int j = 0; j < 6; ++j)
                gll16(src + (j * 256 + tid) * 16, dstb + (j * 256 + tid) * 16);
        }
        if (c > 0 && wave == 0) {   // flush chunk c-1 stats (buffer 1-p)
            float4 q4 = *(const float4*)&statsL[((1 - p) * 64 + lane) * 2];
            pslot[(size_t)blockIdx.x * B_ROWS + (c - 1) * 64 + lane] =
                make_float2(fmaxf(q4.x, q4.z), q4.y + q4.w);
        }

        const char* ab = lds + p * 24576;
        floatx4 acc[2][4];
        #pragma unroll
        for (int mi = 0; mi < 2; ++mi)
            #pragma unroll
            for (int ni = 0; ni < 4; ++ni) {
                floatx4 z = {0.f, 0.f, 0.f, 0.f};
                acc[mi][ni] = z;
            }
        #pragma unroll
        for (int ks = 0; ks < 6; ++ks) {
            bf16x8 a0 = *(const bf16x8*)(ab +
                (((ks * 4 + quad) * 64) + rg * 32 + mrow) * 16);
            bf16x8 a1 = *(const bf16x8*)(ab +
                (((ks * 4 + quad) * 64) + rg * 32 + 16 + mrow) * 16);
            #pragma unroll
            for (int ni = 0; ni < 4; ++ni)
                acc[0][ni] = __builtin_amdgcn_mfma_f32_16x16x32_bf16(
                    a0, bfr[ks][ni], acc[0][ni], 0, 0, 0);
            #pragma unroll
            for (int ni = 0; ni < 4; ++ni)
                acc[1][ni] = __builtin_amdgcn_mfma_f32_16x16x32_bf16(
                    a1, bfr[ks][ni], acc[1][ni], 0, 0, 0);
        }

        // fixed-base-30 stats, DPP rotate-reduce over the 16 col lanes
        #pragma unroll
        for (int mi = 0; mi < 2; ++mi)
            #pragma unroll
            for (int r = 0; r < 4; ++r) {
                float v0 = acc[mi][0][r], v1 = acc[mi][1][r];
                float v2 = acc[mi][2][r], v3 = acc[mi][3][r];
                float m = fmaxf(fmaxf(v0, v1), fmaxf(v2, v3));
                float s = exp2f(fmaf(v0, L2E30, -L2E30))
                        + exp2f(fmaf(v1, L2E30, -L2E30))
                        + exp2f(fmaf(v2, L2E30, -L2E30))
                        + exp2f(fmaf(v3, L2E30, -L2E30));
                s += ror16<1>(s); s += ror16<2>(s);
                s += ror16<4>(s); s += ror16<8>(s);
                m = fmaxf(m, ror16<1>(m)); m = fmaxf(m, ror16<2>(m));
                m = fmaxf(m, ror16<4>(m)); m = fmaxf(m, ror16<8>(m));
                if (mrow == mi * 4 + r)
                    statsL[(p * 64 + rg * 32 + mi * 16 + quad * 4 + r) * 2 + cgr] =
                        make_float2(m, s);
            }
    }
    __syncthreads();
    if (wave == 0) {   // last chunk (parity 1)
        float4 q4 = *(const float4*)&statsL[(64 + lane) * 2];
        pslot[(size_t)blockIdx.x * B_ROWS + (NCHUNKR - 1) * 64 + lane] =
            make_float2(fmaxf(q4.x, q4.z), q4.y + q4.w);
    }
}

// ---------------------------------------------------------------------------
// Finalize: merge 784 partials/row, ArcFace margin correction (recomputes
// ||w_lab|| inline), loss+prec1; last block writes d_out.
// ---------------------------------------------------------------------------
__global__ __launch_bounds__(256)
void finalize_kernel(const float2* __restrict__ pslot,
                     const float* __restrict__ xnf, const float* __restrict__ w,
                     const int* __restrict__ label,
                     float* __restrict__ accum, float* __restrict__ out)
{
    __shared__ float2 red[4][64];
    const int t = threadIdx.x, rr = t & 63, g = t >> 6;
    {
        const int row = blockIdx.x * 64 + rr;
        float M = -1e30f, L = 0.f;
        for (int s = g; s < NTILE_B; s += 4) {
            float2 p2 = pslot[(size_t)s * B_ROWS + row];
            M = fmaxf(M, p2.x);
            L += p2.y;
        }
        red[g][rr] = make_float2(M, L);
    }
    __syncthreads();
    if (t < 64) {
        const int row = blockIdx.x * 64 + t;
        float2 p0 = red[0][t], p1 = red[1][t], p2 = red[2][t], p3 = red[3][t];
        float Mc = fmaxf(fmaxf(p0.x, p1.x), fmaxf(p2.x, p3.x));  // max cosine
        float L  = p0.y + p1.y + p2.y + p3.y;

        const int lab = label[row];
        const float4* xr = (const float4*)(xnf + (size_t)row * DIM);
        const float4* wr = (const float4*)(w + (size_t)lab * DIM);
        float dot = 0.f, nw = 0.f;
        #pragma unroll
        for (int q = 0; q < 48; ++q) {
            float4 a = xr[q], b = wr[q];
            dot += a.x * b.x + a.y * b.y + a.z * b.z + a.w * b.w;
            nw  += b.x * b.x + b.y * b.y + b.z * b.z + b.w * b.w;
        }
        float cosl    = dot * (1.0f / fmaxf(sqrtf(nw), 1e-12f));
        float t_plain = S_SCALE * cosl;
        float sine    = sqrtf(fmaxf(0.f, fminf(1.f, 1.f - cosl * cosl)));
        float phi     = cosl * COS_M - sine * SIN_M;
        float modv    = ((cosl - TH_C) > 0.f) ? phi : (cosl - MM_C);
        float t_mod   = S_SCALE * modv;

        float Ladj = L - __expf(t_plain - 30.0f) + __expf(t_mod - 30.0f);
        Ladj = fmaxf(Ladj, 1e-37f);
        float loss = (30.0f + logf(Ladj)) - t_mod;
        float corr = (t_mod > S_SCALE * Mc) ? 1.f : 0.f;

        #pragma unroll
        for (int off = 32; off > 0; off >>= 1) {
            loss += __shfl_xor(loss, off);
            corr += __shfl_xor(corr, off);
        }
        if (t == 0) {
            atomicAdd(&accum[0], loss);
            atomicAdd(&accum[1], corr);
            __threadfence();
            int old = atomicAdd((int*)accum + 2, 1);
            if (old == (int)gridDim.x - 1) {
                float a0 = atomicAdd(&accum[0], 0.0f);
                float a1 = atomicAdd(&accum[1], 0.0f);
                out[0] = a0 * (1.0f / (float)B_ROWS);
                out[1] = a1 * (100.0f / (float)B_ROWS);
            }
        }
    }
}

// ---------------------------------------------------------------------------
extern "C" void kernel_launch(void* const* d_in, const int* in_sizes, int n_in,
                              void* d_out, int out_size, void* d_ws, size_t ws_size,
                              hipStream_t stream)
{
    const float* x     = (const float*)d_in[0];
    const float* w     = (const float*)d_in[1];
    const int*   label = (const int*)d_in[2];
    float* out = (float*)d_out;

    char* ws = (char*)d_ws;
    size_t off = 0;
    float* accum = (float*)(ws + off);                 off += 256;
    float* xnf   = (float*)(ws + off);                 off += (size_t)B_ROWS * DIM * 4;       // 786432
    unsigned short* asw = (unsigned short*)(ws + off); off += (size_t)NCHUNKR * ASEG_CH * 16;  // 393216
    float2* pslot = (float2*)(ws + off);               off += (size_t)NTILE_B * B_ROWS * 8;    // 6422528

    hipMemsetAsync(accum, 0, 16, stream);

    prep_kernel<<<dim3(8), dim3(256), 0, stream>>>(x, xnf, asw);
    gemm_stats_kernel<<<dim3(NTILE_B), dim3(256), 0, stream>>>(w, asw, pslot);
    finalize_kernel<<<dim3(B_ROWS / 64), dim3(256), 0, stream>>>(
        pslot, xnf, w, label, accum, out);
}

// Round 7
// 249.288 us; speedup vs baseline: 1.1134x; 1.0495x over previous
//
#include <hip/hip_runtime.h>
#include <math.h>

#define B_ROWS   1024
#define DIM      192
#define NCLS     100000
#define S_SCALE  30.0f
#define COS_M    0.98006657784124163f
#define SIN_M    0.19866933079506122f
#define TH_C     (-0.98006657784124163f)
#define MM_C     0.039733866159012243f
#define L2E30    43.2808512266689f      // 30 * log2(e)

#define NTILE_B  784      // 128-class tiles (784*128 = 100352)
#define NCHUNKR  16       // 64-row chunks of A
#define ASEG_CH  1536     // segs per A chunk: 24 k8-groups * 64 rows
#define NSLOT    1568     // stats slots: tile * 2 csel halves

typedef float floatx4 __attribute__((ext_vector_type(4)));
typedef __bf16 bf16x8 __attribute__((ext_vector_type(8)));

__device__ __forceinline__ unsigned int f2bf(float x) {
    unsigned int u = __float_as_uint(x);
    u = (u + 0x7fffu + ((u >> 16) & 1u)) >> 16;   // RNE
    return u;
}
__device__ __forceinline__ unsigned int pack2(float lo, float hi) {
    return f2bf(lo) | (f2bf(hi) << 16);
}
// raw v_exp_f32 (args here are in [-87, 1] — safe range, no libm guards needed)
__device__ __forceinline__ float fexp2(float x) {
#if __has_builtin(__builtin_amdgcn_exp2f)
    return __builtin_amdgcn_exp2f(x);
#else
    float r; __asm__("v_exp_f32 %0, %1" : "=v"(r) : "v"(x)); return r;
#endif
}
// 16-lane rotate (DPP row_ror:N) — reduce over the C-layout col lanes
template <int N>
__device__ __forceinline__ float ror16(float x) {
    return __int_as_float(__builtin_amdgcn_mov_dpp(
        __float_as_int(x), 0x120 | N, 0xF, 0xF, false));
}

// ---------------------------------------------------------------------------
// Prep (x only): L2-normalize + bf16 pack + MFMA-order swizzle -> asw.
// Block 0 also zeroes the accumulator (replaces a memset dispatch).
// Thread pair (2r, 2r+1) owns row r; each thread holds half a row.
// ---------------------------------------------------------------------------
__global__ __launch_bounds__(256)
void prep_kernel(const float* __restrict__ x, unsigned short* __restrict__ asw,
                 float* __restrict__ accum)
{
    const int ab = blockIdx.x;            // 0..7
    const int t = threadIdx.x;
    if (ab == 0 && t < 4) accum[t] = 0.0f;
    const int r = t >> 1, half = t & 1;
    const int row = ab * 128 + r;
    const int c = ab * 2 + (r >> 6);      // A chunk index (64-row chunks)
    const int r64 = r & 63;

    float4 buf[24];
    float s = 0.f;
    const float4* sp = (const float4*)(x + (size_t)row * DIM) + half * 24;
    #pragma unroll
    for (int q = 0; q < 24; ++q) {
        float4 v = sp[q];
        buf[q] = v;
        s += v.x * v.x + v.y * v.y + v.z * v.z + v.w * v.w;
    }
    s += __shfl_xor(s, 1);
    const float inv = 1.0f / fmaxf(sqrtf(s), 1e-12f);
    #pragma unroll
    for (int j = 0; j < 12; ++j) {
        const int k8 = half * 12 + j;
        uint4 o;
        float4 a0 = buf[2 * j], a1 = buf[2 * j + 1];
        o.x = pack2(a0.x * inv, a0.y * inv);
        o.y = pack2(a0.z * inv, a0.w * inv);
        o.z = pack2(a1.x * inv, a1.y * inv);
        o.w = pack2(a1.z * inv, a1.w * inv);
        *(uint4*)(asw + ((size_t)c * ASEG_CH + k8 * 64 + r64) * 8) = o;
    }
}

// ---------------------------------------------------------------------------
// GEMM + fused fixed-base softmax stats — BARRIER-FREE K-loop.
// One block per 128-class tile. Phase 1: normalize+pack this block's w rows
// into LDS (w read once grid-wide). Phase 2: pull B frags to registers
// (96 VGPR/wave); LDS dead after this, ONE barrier total. Phase 3: each wave
// loads its own A fragments straight from global (asw is 384 KB, L2-hot) —
// no LDS, no syncthreads; per-chunk stats DPP-reduced and written to the
// wave's own (tile, csel-half) slot as packed bf16 (m, s).
// ---------------------------------------------------------------------------
__global__ __launch_bounds__(256, 3)
void gemm_stats_kernel(const float* __restrict__ w,
                       const unsigned short* __restrict__ asw,
                       unsigned int* __restrict__ pslot)
{
    __shared__ __align__(16) char lds[49152];
    const int tid  = threadIdx.x;
    const int wave = tid >> 6;
    const int lane = tid & 63;
    const int quad = lane >> 4;
    const int mrow = lane & 15;
    const int rg   = wave >> 1;     // row group (32 rows of each 64-row chunk)
    const int cgr  = wave & 1;      // col group (64 cols)

    // ---- phase 1: normalize + pack this block's 128 w rows into LDS ----
    {
        const int r = tid >> 1, half = tid & 1;
        const int col = blockIdx.x * 128 + r;
        const bool live = (col < NCLS);
        float4 buf[24];
        float s = 0.f;
        if (live) {
            const float4* sp = (const float4*)(w + (size_t)col * DIM) + half * 24;
            #pragma unroll
            for (int q = 0; q < 24; ++q) {
                float4 v = sp[q];
                buf[q] = v;
                s += v.x * v.x + v.y * v.y + v.z * v.z + v.w * v.w;
            }
        }
        s += __shfl_xor(s, 1);
        const float inv = live ? (1.0f / fmaxf(sqrtf(s), 1e-12f)) : 0.0f;
        #pragma unroll
        for (int j = 0; j < 12; ++j) {
            const int k8 = half * 12 + j;
            uint4 o = make_uint4(0u, 0u, 0u, 0u);
            if (live) {
                float4 a0 = buf[2 * j], a1 = buf[2 * j + 1];
                o.x = pack2(a0.x * inv, a0.y * inv);
                o.y = pack2(a0.z * inv, a0.w * inv);
                o.z = pack2(a1.x * inv, a1.y * inv);
                o.w = pack2(a1.z * inv, a1.w * inv);
            }
            *(uint4*)(lds + (size_t)(k8 * 128 + r) * 16) = o;
        }
    }
    __syncthreads();        // the ONLY barrier in this kernel

    // ---- phase 2: pull B fragments to registers ----
    bf16x8 bfr[6][4];
    #pragma unroll
    for (int ks = 0; ks < 6; ++ks)
        #pragma unroll
        for (int ni = 0; ni < 4; ++ni)
            bfr[ks][ni] = *(const bf16x8*)(lds +
                (((ks * 4 + quad) * 128) + cgr * 64 + ni * 16 + mrow) * 16);

    // ---- phase 3: barrier-free A streaming, global -> VGPR frags ----
    const int slot = blockIdx.x * 2 + cgr;
    #pragma unroll 2
    for (int c = 0; c < NCHUNKR; ++c) {
        const unsigned short* ab = asw + (size_t)c * ASEG_CH * 8;
        floatx4 acc[2][4];
        #pragma unroll
        for (int mi = 0; mi < 2; ++mi)
            #pragma unroll
            for (int ni = 0; ni < 4; ++ni) {
                floatx4 z = {0.f, 0.f, 0.f, 0.f};
                acc[mi][ni] = z;
            }
        #pragma unroll
        for (int ks = 0; ks < 6; ++ks) {
            bf16x8 a0 = *(const bf16x8*)(ab +
                (size_t)(((ks * 4 + quad) * 64) + rg * 32 + mrow) * 8);
            bf16x8 a1 = *(const bf16x8*)(ab +
                (size_t)(((ks * 4 + quad) * 64) + rg * 32 + 16 + mrow) * 8);
            #pragma unroll
            for (int ni = 0; ni < 4; ++ni)
                acc[0][ni] = __builtin_amdgcn_mfma_f32_16x16x32_bf16(
                    a0, bfr[ks][ni], acc[0][ni], 0, 0, 0);
            #pragma unroll
            for (int ni = 0; ni < 4; ++ni)
                acc[1][ni] = __builtin_amdgcn_mfma_f32_16x16x32_bf16(
                    a1, bfr[ks][ni], acc[1][ni], 0, 0, 0);
        }

        // fixed-base-30 stats; DPP rotate-reduce over the 16 col lanes;
        // each wave owns its slot -> direct packed-bf16 global write.
        #pragma unroll
        for (int mi = 0; mi < 2; ++mi)
            #pragma unroll
            for (int r = 0; r < 4; ++r) {
                float v0 = acc[mi][0][r], v1 = acc[mi][1][r];
                float v2 = acc[mi][2][r], v3 = acc[mi][3][r];
                float m = fmaxf(fmaxf(v0, v1), fmaxf(v2, v3));
                float s = fexp2(fmaf(v0, L2E30, -L2E30))
                        + fexp2(fmaf(v1, L2E30, -L2E30))
                        + fexp2(fmaf(v2, L2E30, -L2E30))
                        + fexp2(fmaf(v3, L2E30, -L2E30));
                s += ror16<1>(s); s += ror16<2>(s);
                s += ror16<4>(s); s += ror16<8>(s);
                m = fmaxf(m, ror16<1>(m)); m = fmaxf(m, ror16<2>(m));
                m = fmaxf(m, ror16<4>(m)); m = fmaxf(m, ror16<8>(m));
                if (mrow == mi * 4 + r)
                    pslot[(size_t)slot * B_ROWS +
                          c * 64 + rg * 32 + mi * 16 + quad * 4 + r] = pack2(m, s);
            }
    }
}

// ---------------------------------------------------------------------------
// Finalize: merge 1568 packed slots/row, ArcFace margin correction
// (renormalizes from raw x and w inline), loss+prec1; last block writes out.
// grid(32) x 256: 32 rows/block, 8 slot-groups, coalesced slot-major reads.
// ---------------------------------------------------------------------------
__global__ __launch_bounds__(256)
void finalize_kernel(const unsigned int* __restrict__ pslot,
                     const float* __restrict__ x, const float* __restrict__ w,
                     const int* __restrict__ label,
                     float* __restrict__ accum, float* __restrict__ out)
{
    __shared__ float2 red[8][32];
    const int t = threadIdx.x, rr = t & 31, g = t >> 5;
    {
        const int row = blockIdx.x * 32 + rr;
        float M = -1e30f, L = 0.f;
        for (int s = g; s < NSLOT; s += 8) {
            unsigned int u = pslot[(size_t)s * B_ROWS + row];
            M = fmaxf(M, __uint_as_float(u << 16));
            L += __uint_as_float(u & 0xFFFF0000u);
        }
        red[g][rr] = make_float2(M, L);
    }
    __syncthreads();
    if (t < 32) {
        const int row = blockIdx.x * 32 + t;
        float Mc = -1e30f, L = 0.f;
        #pragma unroll
        for (int g2 = 0; g2 < 8; ++g2) {
            float2 p = red[g2][t];
            Mc = fmaxf(Mc, p.x);
            L += p.y;
        }

        const int lab = label[row];
        const float4* xr = (const float4*)(x + (size_t)row * DIM);
        const float4* wr = (const float4*)(w + (size_t)lab * DIM);
        float dot = 0.f, nx = 0.f, nw = 0.f;
        #pragma unroll
        for (int q = 0; q < 48; ++q) {
            float4 a = xr[q], b = wr[q];
            dot += a.x * b.x + a.y * b.y + a.z * b.z + a.w * b.w;
            nx  += a.x * a.x + a.y * a.y + a.z * a.z + a.w * a.w;
            nw  += b.x * b.x + b.y * b.y + b.z * b.z + b.w * b.w;
        }
        float cosl    = dot / fmaxf(sqrtf(nx) * sqrtf(nw), 1e-12f);
        float t_plain = S_SCALE * cosl;
        float sine    = sqrtf(fmaxf(0.f, fminf(1.f, 1.f - cosl * cosl)));
        float phi     = cosl * COS_M - sine * SIN_M;
        float modv    = ((cosl - TH_C) > 0.f) ? phi : (cosl - MM_C);
        float t_mod   = S_SCALE * modv;

        float Ladj = L - __expf(t_plain - 30.0f) + __expf(t_mod - 30.0f);
        Ladj = fmaxf(Ladj, 1e-37f);
        float loss = (30.0f + logf(Ladj)) - t_mod;
        float corr = (t_mod > S_SCALE * Mc) ? 1.f : 0.f;

        #pragma unroll
        for (int off = 16; off > 0; off >>= 1) {
            loss += __shfl_xor(loss, off);
            corr += __shfl_xor(corr, off);
        }
        if (t == 0) {
            atomicAdd(&accum[0], loss);
            atomicAdd(&accum[1], corr);
            __threadfence();
            int old = atomicAdd((int*)accum + 2, 1);
            if (old == (int)gridDim.x - 1) {
                float a0 = atomicAdd(&accum[0], 0.0f);
                float a1 = atomicAdd(&accum[1], 0.0f);
                out[0] = a0 * (1.0f / (float)B_ROWS);
                out[1] = a1 * (100.0f / (float)B_ROWS);
            }
        }
    }
}

// ---------------------------------------------------------------------------
extern "C" void kernel_launch(void* const* d_in, const int* in_sizes, int n_in,
                              void* d_out, int out_size, void* d_ws, size_t ws_size,
                              hipStream_t stream)
{
    const float* x     = (const float*)d_in[0];
    const float* w     = (const float*)d_in[1];
    const int*   label = (const int*)d_in[2];
    float* out = (float*)d_out;

    char* ws = (char*)d_ws;
    size_t off = 0;
    float* accum = (float*)(ws + off);                 off += 256;
    unsigned short* asw = (unsigned short*)(ws + off); off += (size_t)NCHUNKR * ASEG_CH * 16; // 393216
    unsigned int* pslot = (unsigned int*)(ws + off);   off += (size_t)NSLOT * B_ROWS * 4;     // 6422528

    prep_kernel<<<dim3(8), dim3(256), 0, stream>>>(x, asw, accum);
    gemm_stats_kernel<<<dim3(NTILE_B), dim3(256), 0, stream>>>(w, asw, pslot);
    finalize_kernel<<<dim3(B_ROWS / 32), dim3(256), 0, stream>>>(
        pslot, x, w, label, accum, out);
}